// Round 1
// 192.339 us; speedup vs baseline: 1.0158x; 1.0158x over previous
//
#include <hip/hip_runtime.h>

#define M_DIM 8192
#define N_DIM 2048
#define K_DIM 2048

#define BM 256
#define BN 256
#define BK 64
#define NT (K_DIM / BK)

#define AS1 __attribute__((address_space(1)))
#define AS3 __attribute__((address_space(3)))

typedef float f32x4 __attribute__((ext_vector_type(4)));
typedef short s16x8 __attribute__((ext_vector_type(8)));

__device__ __forceinline__ unsigned short f2bf(float f) {
  unsigned int u = __float_as_uint(f);
  u += 0x7FFFu + ((u >> 16) & 1u);   // round-to-nearest-even
  return (unsigned short)(u >> 16);
}

// ---------------------------------------------------------------------------
// Kernel 1: per-token asymmetric int8 fake-quant, output bf16 x_dq [M][K]
// ---------------------------------------------------------------------------
__global__ __launch_bounds__(256) void quant_x_kernel(
    const float* __restrict__ x, unsigned short* __restrict__ A) {
  const int t   = blockIdx.x;
  const int tid = threadIdx.x;
  const float4* r4 = (const float4*)(x + (size_t)t * K_DIM);
  float4 v0 = r4[tid];
  float4 v1 = r4[tid + 256];

  float mn = fminf(fminf(fminf(v0.x, v0.y), fminf(v0.z, v0.w)),
                   fminf(fminf(v1.x, v1.y), fminf(v1.z, v1.w)));
  float mx = fmaxf(fmaxf(fmaxf(v0.x, v0.y), fmaxf(v0.z, v0.w)),
                   fmaxf(fmaxf(v1.x, v1.y), fmaxf(v1.z, v1.w)));
#pragma unroll
  for (int off = 32; off > 0; off >>= 1) {
    mn = fminf(mn, __shfl_xor(mn, off));
    mx = fmaxf(mx, __shfl_xor(mx, off));
  }
  __shared__ float smn[4], smx[4];
  if ((tid & 63) == 0) { smn[tid >> 6] = mn; smx[tid >> 6] = mx; }
  __syncthreads();
  mn = fminf(fminf(smn[0], smn[1]), fminf(smn[2], smn[3]));
  mx = fmaxf(fmaxf(smx[0], smx[1]), fmaxf(smx[2], smx[3]));
  mn = fminf(mn, 0.0f);
  mx = fmaxf(mx, 0.0f);

  float scale = (mx - mn) / 255.0f;                 // (QMAX-QMIN)=255
  scale = fmaxf(scale, 1.1920928955078125e-07f);    // f32 eps = 2^-23
  const float inv = 1.0f / scale;                   // one IEEE div per token
  float zp = -128.0f - rintf(mn * inv);
  zp = fminf(fmaxf(zp, -128.0f), 127.0f);

  ushort4* Ao = (ushort4*)(A + (size_t)t * K_DIM);
  {
    float q; ushort4 r;
    q = rintf(v0.x * inv) + zp; q = fminf(fmaxf(q, -128.f), 127.f); r.x = f2bf((q - zp) * scale);
    q = rintf(v0.y * inv) + zp; q = fminf(fmaxf(q, -128.f), 127.f); r.y = f2bf((q - zp) * scale);
    q = rintf(v0.z * inv) + zp; q = fminf(fmaxf(q, -128.f), 127.f); r.z = f2bf((q - zp) * scale);
    q = rintf(v0.w * inv) + zp; q = fminf(fmaxf(q, -128.f), 127.f); r.w = f2bf((q - zp) * scale);
    Ao[tid] = r;
  }
  {
    float q; ushort4 r;
    q = rintf(v1.x * inv) + zp; q = fminf(fmaxf(q, -128.f), 127.f); r.x = f2bf((q - zp) * scale);
    q = rintf(v1.y * inv) + zp; q = fminf(fmaxf(q, -128.f), 127.f); r.y = f2bf((q - zp) * scale);
    q = rintf(v1.z * inv) + zp; q = fminf(fmaxf(q, -128.f), 127.f); r.z = f2bf((q - zp) * scale);
    q = rintf(v1.w * inv) + zp; q = fminf(fmaxf(q, -128.f), 127.f); r.w = f2bf((q - zp) * scale);
    Ao[tid + 256] = r;
  }
}

// ---------------------------------------------------------------------------
// Kernel 2: grouped int4 dequant of W -> bf16 w_dq [N][K]
// ---------------------------------------------------------------------------
__global__ __launch_bounds__(256) void prep_w_kernel(
    const int* __restrict__ w, const float* __restrict__ ws,
    const float* __restrict__ wz, unsigned short* __restrict__ W) {
  const int idx = blockIdx.x * 256 + threadIdx.x;  // one 8-elem chunk
  const int o  = idx >> 8;                         // 2048/8 = 256 chunks/row
  const int ii = (idx & 255) * 8;
  const int g  = ii >> 5;                          // GROUPSIZE=32, 8|32
  const float s = ws[o * 64 + g];
  const float z = wz[o * 64 + g];
  const int4* wp = (const int4*)(w + (size_t)o * K_DIM + ii);
  int4 a = wp[0], b = wp[1];
  ushort4 r0, r1;
  r0.x = f2bf(((float)a.x - z) * s);
  r0.y = f2bf(((float)a.y - z) * s);
  r0.z = f2bf(((float)a.z - z) * s);
  r0.w = f2bf(((float)a.w - z) * s);
  r1.x = f2bf(((float)b.x - z) * s);
  r1.y = f2bf(((float)b.y - z) * s);
  r1.z = f2bf(((float)b.z - z) * s);
  r1.w = f2bf(((float)b.w - z) * s);
  ushort4* Wo = (ushort4*)(W + (size_t)o * K_DIM + ii);
  Wo[0] = r0;
  Wo[1] = r1;
}

// ---------------------------------------------------------------------------
// Kernel 3: C[M][N] = A[M][K] * B[N][K]^T, bf16 in, f32 out.
// 8-phase 256x256 schedule (learn_hip m201 template, plain HIP):
//   512 threads = 8 waves (2M x 4N), wave tile 128x64, acc 8x4 of 16x16x32.
//   LDS 128 KiB: A,B double-buffered, staged via global_load_lds width=16
//   with pre-swizzled global source (chunk c stored at slot c^(row&7)) ->
//   conflict-free ds_read_b128 fragment reads (measured 0 conflicts).
//   Per K-tile: 4 phases {ds_read quadrant | issue prefetch -> s_barrier ->
//   setprio(1) 16xMFMA setprio(0) -> s_barrier}. Prefetch of tile t+1 is
//   front-loaded into phases 0-1 (dest buffer holds dead tile t-1 => no
//   WAR race), so the single vmcnt(0) at the tile boundary sits ~2.5
//   phases after the last issue: the drain is hidden, unlike __syncthreads
//   which drains vmcnt(0) at EVERY barrier (the old ~920 TF ceiling).
// ---------------------------------------------------------------------------

#define PHASE_BAR()                                  \
  do {                                               \
    __builtin_amdgcn_sched_barrier(0);               \
    __builtin_amdgcn_s_barrier();                    \
    __builtin_amdgcn_sched_barrier(0);               \
  } while (0)

#define READ_AF(MH)                                                         \
  do {                                                                      \
    _Pragma("unroll") for (int i = 0; i < 4; ++i) {                         \
      _Pragma("unroll") for (int kk = 0; kk < 2; ++kk) {                    \
        af[i][kk] = *(const s16x8*)&Ab[aoff[(MH) * 4 + i] ^ (kk * 32)];     \
      }                                                                     \
    }                                                                       \
  } while (0)

#define READ_BF(NH)                                                         \
  do {                                                                      \
    _Pragma("unroll") for (int j = 0; j < 2; ++j) {                         \
      _Pragma("unroll") for (int kk = 0; kk < 2; ++kk) {                    \
        bf[NH][j][kk] = *(const s16x8*)&Bb[boff[(NH) * 2 + j] ^ (kk * 32)]; \
      }                                                                     \
    }                                                                       \
  } while (0)

#define MFMA_QUAD(MH, NH)                                                   \
  do {                                                                      \
    __builtin_amdgcn_s_setprio(1);                                          \
    _Pragma("unroll") for (int kk = 0; kk < 2; ++kk) {                      \
      _Pragma("unroll") for (int i = 0; i < 4; ++i) {                       \
        _Pragma("unroll") for (int j = 0; j < 2; ++j) {                     \
          acc[(MH) * 4 + i][(NH) * 2 + j] =                                 \
              __builtin_amdgcn_mfma_f32_16x16x32_bf16(                      \
                  af[i][kk], bf[NH][j][kk],                                 \
                  acc[(MH) * 4 + i][(NH) * 2 + j], 0, 0, 0);                \
        }                                                                   \
      }                                                                     \
    }                                                                       \
    __builtin_amdgcn_s_setprio(0);                                          \
  } while (0)

#define STAGE_A(KN, DSTP)                                                   \
  do {                                                                      \
    _Pragma("unroll") for (int j = 0; j < 4; ++j) {                         \
      __builtin_amdgcn_global_load_lds(                                     \
          (const AS1 void*)(ag + (size_t)j * 64 * K_DIM + (KN)),            \
          (AS3 void*)(&As[(DSTP) * (BM * BK) + tid * 8 + j * 4096]),        \
          16, 0, 0);                                                        \
    }                                                                       \
  } while (0)

#define STAGE_B(KN, DSTP)                                                   \
  do {                                                                      \
    _Pragma("unroll") for (int j = 0; j < 4; ++j) {                         \
      __builtin_amdgcn_global_load_lds(                                     \
          (const AS1 void*)(bg + (size_t)j * 64 * K_DIM + (KN)),            \
          (AS3 void*)(&Bs[(DSTP) * (BN * BK) + tid * 8 + j * 4096]),        \
          16, 0, 0);                                                        \
    }                                                                       \
  } while (0)

__global__ __launch_bounds__(512, 2) void gemm_kernel(
    const unsigned short* __restrict__ A,
    const unsigned short* __restrict__ B,
    float* __restrict__ C) {
  __shared__ unsigned short As[2 * BM * BK];  // 64 KB, double-buffered
  __shared__ unsigned short Bs[2 * BN * BK];  // 64 KB, double-buffered

  const int tid = threadIdx.x;
  // XCD swizzle: linear dispatch id = by*8+bx, id%8 ~ XCD. Each XCD gets a
  // contiguous 4-slab M range x full N (bijective, nwg=256 = 8*32).
  const int id  = blockIdx.y * 8 + blockIdx.x;
  const int nid = (id & 7) * 32 + (id >> 3);
  const int bm  = (nid >> 3) * BM;
  const int bn  = (nid & 7) * BN;

  const int lane  = tid & 63;
  const int wv    = tid >> 6;
  const int waveM = (wv >> 2) * 128;   // 2 M-waves
  const int waveN = (wv & 3) * 64;     // 4 N-waves
  const int quad  = lane >> 4;
  const int l16   = lane & 15;

  // --- staging: row = trow + j*64, global chunk (phys) = (tid&7)^(trow&7),
  // LDS dest linear at tid*16B (wave-uniform base + lane*16 requirement).
  const int trow = tid >> 3;                    // 0..63
  const int phys = (tid & 7) ^ (trow & 7);
  const unsigned short* ag = A + (size_t)(bm + trow) * K_DIM + phys * 8;
  const unsigned short* bg = B + (size_t)(bn + trow) * K_DIM + phys * 8;

  // --- fragment read offsets (undo swizzle); row&7 == l16&7 for all frags
  int aoff[8], boff[4];
#pragma unroll
  for (int mi = 0; mi < 8; ++mi)
    aoff[mi] = (waveM + mi * 16 + l16) * BK + ((quad ^ (l16 & 7)) * 8);
#pragma unroll
  for (int ni = 0; ni < 4; ++ni)
    boff[ni] = (waveN + ni * 16 + l16) * BK + ((quad ^ (l16 & 7)) * 8);

  f32x4 acc[8][4] = {};

  // --- prologue: stage tile 0 into buffer 0, full drain (once, cold)
  STAGE_A(0, 0);
  STAGE_B(0, 0);
  __builtin_amdgcn_sched_barrier(0);
  asm volatile("s_waitcnt vmcnt(0)" ::: "memory");
  __builtin_amdgcn_s_barrier();
  __builtin_amdgcn_sched_barrier(0);

  for (int t = 0; t < NT; ++t) {
    const int p = t & 1;
    const unsigned short* Ab = &As[p * (BM * BK)];
    const unsigned short* Bb = &Bs[p * (BN * BK)];
    const int kn = (t + 1) * BK;
    const bool pref = (t + 1) < NT;

    s16x8 af[4][2];        // current M-half A fragments
    s16x8 bf[2][2][2];     // both N-half B fragment sets (held across phases)

    // ---- phase 0: read af(m0)+bf(n0) [12 ds_read]; issue A(t+1) prefetch
    READ_AF(0);
    READ_BF(0);
    if (pref) STAGE_A(kn, p ^ 1);
    PHASE_BAR();
    MFMA_QUAD(0, 0);
    PHASE_BAR();

    // ---- phase 1: read bf(n1) [4 ds_read]; issue B(t+1) prefetch
    READ_BF(1);
    if (pref) STAGE_B(kn, p ^ 1);
    PHASE_BAR();
    MFMA_QUAD(0, 1);
    PHASE_BAR();

    // ---- phase 2: read af(m1) [8 ds_read]; reuse bf(n1)
    READ_AF(1);
    PHASE_BAR();
    MFMA_QUAD(1, 1);
    PHASE_BAR();

    // ---- phase 3: no reads (reuse af(m1), bf(n0)); boundary drain AFTER
    // the MFMAs: last prefetch issue was ~2.5 phases ago -> near-free wait.
    MFMA_QUAD(1, 0);
    __builtin_amdgcn_sched_barrier(0);
    asm volatile("s_waitcnt vmcnt(0)" ::: "memory");
    PHASE_BAR();
  }

  // --- epilogue: C/D layout col=lane&15, row=quad*4+reg (unchanged order)
#pragma unroll
  for (int mi = 0; mi < 8; ++mi) {
#pragma unroll
    for (int ni = 0; ni < 4; ++ni) {
      const int o = bn + waveN + ni * 16 + l16;
#pragma unroll
      for (int r = 0; r < 4; ++r) {
        const int row = bm + waveM + mi * 16 + quad * 4 + r;
        C[(size_t)row * N_DIM + o] = acc[mi][ni][r];
      }
    }
  }
}

// ---------------------------------------------------------------------------
extern "C" void kernel_launch(void* const* d_in, const int* in_sizes, int n_in,
                              void* d_out, int out_size, void* d_ws, size_t ws_size,
                              hipStream_t stream) {
  const float* x        = (const float*)d_in[0];
  const int*   w_int    = (const int*)d_in[1];
  const float* w_scales = (const float*)d_in[2];
  const float* w_zeros  = (const float*)d_in[3];
  float* out = (float*)d_out;

  unsigned short* Aq = (unsigned short*)d_ws;                 // 8192*2048 bf16
  unsigned short* Wq = Aq + (size_t)M_DIM * K_DIM;            // 2048*2048 bf16

  quant_x_kernel<<<M_DIM, 256, 0, stream>>>(x, Aq);
  prep_w_kernel<<<(N_DIM * (K_DIM / 8)) / 256, 256, 0, stream>>>(w_int, w_scales, w_zeros, Wq);
  dim3 grid(N_DIM / BN, M_DIM / BM);   // (8, 32) = 256 blocks = 1/CU
  gemm_kernel<<<grid, 512, 0, stream>>>(Aq, Wq, out);
}

// Round 3
// 189.021 us; speedup vs baseline: 1.0336x; 1.0176x over previous
//
#include <hip/hip_runtime.h>

#define M_DIM 8192
#define N_DIM 2048
#define K_DIM 2048

#define BM 256
#define BN 256
#define BK 64
#define NT (K_DIM / BK)

#define AS1 __attribute__((address_space(1)))
#define AS3 __attribute__((address_space(3)))

typedef float f32x4 __attribute__((ext_vector_type(4)));
typedef short s16x8 __attribute__((ext_vector_type(8)));

__device__ __forceinline__ unsigned short f2bf(float f) {
  unsigned int u = __float_as_uint(f);
  u += 0x7FFFu + ((u >> 16) & 1u);   // round-to-nearest-even
  return (unsigned short)(u >> 16);
}

// ---------------------------------------------------------------------------
// Kernel 1 (merged): blocks [0, M_DIM) do per-token int8 fake-quant of x;
// blocks [M_DIM, ...) do grouped int4 dequant of W. Independent halves,
// one dispatch; internals byte-identical to the verified two-kernel split.
// ---------------------------------------------------------------------------
__global__ __launch_bounds__(256) void prep_kernel(
    const float* __restrict__ x, const int* __restrict__ w,
    const float* __restrict__ ws, const float* __restrict__ wz,
    unsigned short* __restrict__ A, unsigned short* __restrict__ W) {
  const int tid = threadIdx.x;
  if (blockIdx.x < M_DIM) {
    // ---- per-token asymmetric int8 fake-quant, output bf16 A[M][K]
    const int t = blockIdx.x;
    const float4* r4 = (const float4*)(x + (size_t)t * K_DIM);
    float4 v0 = r4[tid];
    float4 v1 = r4[tid + 256];

    float mn = fminf(fminf(fminf(v0.x, v0.y), fminf(v0.z, v0.w)),
                     fminf(fminf(v1.x, v1.y), fminf(v1.z, v1.w)));
    float mx = fmaxf(fmaxf(fmaxf(v0.x, v0.y), fmaxf(v0.z, v0.w)),
                     fmaxf(fmaxf(v1.x, v1.y), fmaxf(v1.z, v1.w)));
#pragma unroll
    for (int off = 32; off > 0; off >>= 1) {
      mn = fminf(mn, __shfl_xor(mn, off));
      mx = fmaxf(mx, __shfl_xor(mx, off));
    }
    __shared__ float smn[4], smx[4];
    if ((tid & 63) == 0) { smn[tid >> 6] = mn; smx[tid >> 6] = mx; }
    __syncthreads();
    mn = fminf(fminf(smn[0], smn[1]), fminf(smn[2], smn[3]));
    mx = fmaxf(fmaxf(smx[0], smx[1]), fmaxf(smx[2], smx[3]));
    mn = fminf(mn, 0.0f);
    mx = fmaxf(mx, 0.0f);

    float scale = (mx - mn) / 255.0f;                 // (QMAX-QMIN)=255
    scale = fmaxf(scale, 1.1920928955078125e-07f);    // f32 eps = 2^-23
    const float inv = 1.0f / scale;                   // one IEEE div per token
    float zp = -128.0f - rintf(mn * inv);
    zp = fminf(fmaxf(zp, -128.0f), 127.0f);

    ushort4* Ao = (ushort4*)(A + (size_t)t * K_DIM);
    {
      float q; ushort4 r;
      q = rintf(v0.x * inv) + zp; q = fminf(fmaxf(q, -128.f), 127.f); r.x = f2bf((q - zp) * scale);
      q = rintf(v0.y * inv) + zp; q = fminf(fmaxf(q, -128.f), 127.f); r.y = f2bf((q - zp) * scale);
      q = rintf(v0.z * inv) + zp; q = fminf(fmaxf(q, -128.f), 127.f); r.z = f2bf((q - zp) * scale);
      q = rintf(v0.w * inv) + zp; q = fminf(fmaxf(q, -128.f), 127.f); r.w = f2bf((q - zp) * scale);
      Ao[tid] = r;
    }
    {
      float q; ushort4 r;
      q = rintf(v1.x * inv) + zp; q = fminf(fmaxf(q, -128.f), 127.f); r.x = f2bf((q - zp) * scale);
      q = rintf(v1.y * inv) + zp; q = fminf(fmaxf(q, -128.f), 127.f); r.y = f2bf((q - zp) * scale);
      q = rintf(v1.z * inv) + zp; q = fminf(fmaxf(q, -128.f), 127.f); r.z = f2bf((q - zp) * scale);
      q = rintf(v1.w * inv) + zp; q = fminf(fmaxf(q, -128.f), 127.f); r.w = f2bf((q - zp) * scale);
      Ao[tid + 256] = r;
    }
  } else {
    // ---- grouped int4 dequant of W -> bf16 W[N][K]
    const int idx = (blockIdx.x - M_DIM) * 256 + tid;  // one 8-elem chunk
    const int o  = idx >> 8;                           // 2048/8 = 256 chunks/row
    const int ii = (idx & 255) * 8;
    const int g  = ii >> 5;                            // GROUPSIZE=32
    const float s = ws[o * 64 + g];
    const float z = wz[o * 64 + g];
    const int4* wp = (const int4*)(w + (size_t)o * K_DIM + ii);
    int4 a = wp[0], b = wp[1];
    ushort4 r0, r1;
    r0.x = f2bf(((float)a.x - z) * s);
    r0.y = f2bf(((float)a.y - z) * s);
    r0.z = f2bf(((float)a.z - z) * s);
    r0.w = f2bf(((float)a.w - z) * s);
    r1.x = f2bf(((float)b.x - z) * s);
    r1.y = f2bf(((float)b.y - z) * s);
    r1.z = f2bf(((float)b.z - z) * s);
    r1.w = f2bf(((float)b.w - z) * s);
    ushort4* Wo = (ushort4*)(W + (size_t)o * K_DIM + ii);
    Wo[0] = r0;
    Wo[1] = r1;
  }
}

// ---------------------------------------------------------------------------
// Kernel 2: C[M][N] = A[M][K] * B[N][K]^T, bf16 in, f32 out.
// 256x256x64, 8 waves (2M x 4N), 4 phases/K-tile, counted-vmcnt pipeline.
//
// Slot-deadness facts (staging halves vs fragment reads interleave across
// waves, so per-half retirement does NOT hold):
//   - buf p^1 (holds tile kt-1, fully read last iter): writable any phase.
//   - buf p (tile kt): fully dead only after the post-MFMA(1,1) barrier
//     (each wave lgkm-waits its ph2 reads before MFMA(1,1); barrier makes
//     that chip-wide) -> writable from phase 3 on.
// Stage schedule per iter kt (computing buf p = kt&1), 2 vmem instr each:
//   ph0: A-h1(kt+1), B-h0(kt+1) -> buf p^1
//   ph1: B-h1(kt+1)             -> buf p^1
//   ph3: A-h0(kt+2)             -> buf p      (first dead phase)
// Boundary wait (end of ph3): vmcnt(2) — leaves only A-h0(kt+2) in
// flight; confirms all four halves of tile kt+1 (A-h0 from ph3 of iter
// kt-1, rest from ph0/ph1 of this iter). Outstanding ledger per wave:
// <=2 -> +4(ph0) -> +2(ph1) -> +2(ph3) = <=10 -> vmcnt(2). The newest
// confirmed load (B-h1) was issued ~2.5 MFMA-phases earlier, so the wait
// is near-free; vmcnt never drains to 0 except the last two iterations.
// ---------------------------------------------------------------------------

#define PHASE_BAR()                                  \
  do {                                               \
    __builtin_amdgcn_sched_barrier(0);               \
    __builtin_amdgcn_s_barrier();                    \
    __builtin_amdgcn_sched_barrier(0);               \
  } while (0)

#define READ_AF(MH)                                                         \
  do {                                                                      \
    _Pragma("unroll") for (int i = 0; i < 4; ++i) {                         \
      _Pragma("unroll") for (int kk = 0; kk < 2; ++kk) {                    \
        af[i][kk] = *(const s16x8*)&Ab[aoff[(MH) * 4 + i] ^ (kk * 32)];     \
      }                                                                     \
    }                                                                       \
  } while (0)

#define READ_BF(NH)                                                         \
  do {                                                                      \
    _Pragma("unroll") for (int j = 0; j < 2; ++j) {                         \
      _Pragma("unroll") for (int kk = 0; kk < 2; ++kk) {                    \
        bf[NH][j][kk] = *(const s16x8*)&Bb[boff[(NH) * 2 + j] ^ (kk * 32)]; \
      }                                                                     \
    }                                                                       \
  } while (0)

#define MFMA_QUAD(MH, NH)                                                   \
  do {                                                                      \
    __builtin_amdgcn_s_setprio(1);                                          \
    _Pragma("unroll") for (int kk = 0; kk < 2; ++kk) {                      \
      _Pragma("unroll") for (int i = 0; i < 4; ++i) {                       \
        _Pragma("unroll") for (int j = 0; j < 2; ++j) {                     \
          acc[(MH) * 4 + i][(NH) * 2 + j] =                                 \
              __builtin_amdgcn_mfma_f32_16x16x32_bf16(                      \
                  af[i][kk], bf[NH][j][kk],                                 \
                  acc[(MH) * 4 + i][(NH) * 2 + j], 0, 0, 0);                \
        }                                                                   \
      }                                                                     \
    }                                                                       \
    __builtin_amdgcn_s_setprio(0);                                          \
  } while (0)

// One half-tile = 128 rows x 64 cols bf16 = 16 KB = 2 glds rounds of
// (512 threads x 16 B). Round j' = H*2+j covers rows trow + j'*64.
#define STAGE_A_HALF(KN, DSTP, H)                                            \
  do {                                                                       \
    _Pragma("unroll") for (int j = 0; j < 2; ++j) {                          \
      __builtin_amdgcn_global_load_lds(                                      \
          (const AS1 void*)(ag + (size_t)((H) * 2 + j) * 64 * K_DIM + (KN)), \
          (AS3 void*)(&As[(DSTP) * (BM * BK) + ((H) * 2 + j) * 4096 + tid * 8]), \
          16, 0, 0);                                                         \
    }                                                                        \
  } while (0)

#define STAGE_B_HALF(KN, DSTP, H)                                            \
  do {                                                                       \
    _Pragma("unroll") for (int j = 0; j < 2; ++j) {                          \
      __builtin_amdgcn_global_load_lds(                                      \
          (const AS1 void*)(bg + (size_t)((H) * 2 + j) * 64 * K_DIM + (KN)), \
          (AS3 void*)(&Bs[(DSTP) * (BN * BK) + ((H) * 2 + j) * 4096 + tid * 8]), \
          16, 0, 0);                                                         \
    }                                                                        \
  } while (0)

__global__ __launch_bounds__(512, 2) void gemm_kernel(
    const unsigned short* __restrict__ A,
    const unsigned short* __restrict__ B,
    float* __restrict__ C) {
  __shared__ unsigned short As[2 * BM * BK];  // 64 KB, double-buffered
  __shared__ unsigned short Bs[2 * BN * BK];  // 64 KB, double-buffered

  const int tid = threadIdx.x;
  // XCD swizzle: linear dispatch id = by*8+bx, id%8 ~ XCD. Each XCD gets a
  // contiguous 4-slab M range x full N (bijective, nwg=256 = 8*32) -> its
  // 4 MiB A-slab lives in its own L2.
  const int id  = blockIdx.y * 8 + blockIdx.x;
  const int nid = (id & 7) * 32 + (id >> 3);
  const int bm  = (nid >> 3) * BM;
  const int bn  = (nid & 7) * BN;

  const int lane  = tid & 63;
  const int wv    = tid >> 6;
  const int waveM = (wv >> 2) * 128;   // 2 M-waves
  const int waveN = (wv & 3) * 64;     // 4 N-waves
  const int quad  = lane >> 4;
  const int l16   = lane & 15;

  // --- staging: row = trow + round*64, global chunk (phys) = (tid&7)^(trow&7),
  // LDS dest linear at tid*16B (wave-uniform base + lane*16 requirement).
  const int trow = tid >> 3;                    // 0..63
  const int phys = (tid & 7) ^ (trow & 7);
  const unsigned short* ag = A + (size_t)(bm + trow) * K_DIM + phys * 8;
  const unsigned short* bg = B + (size_t)(bn + trow) * K_DIM + phys * 8;

  // --- fragment read offsets (undo swizzle); row&7 == l16&7 for all frags
  int aoff[8], boff[4];
#pragma unroll
  for (int mi = 0; mi < 8; ++mi)
    aoff[mi] = (waveM + mi * 16 + l16) * BK + ((quad ^ (l16 & 7)) * 8);
#pragma unroll
  for (int ni = 0; ni < 4; ++ni)
    boff[ni] = (waveN + ni * 16 + l16) * BK + ((quad ^ (l16 & 7)) * 8);

  f32x4 acc[8][4] = {};

  // --- prologue: K-tile 0 complete (buf 0) + A-h0 of K-tile 1 (buf 1),
  // matching steady state (A-h0(kt+1) is always staged one iter early).
  // vmcnt(2) retires exactly K-tile 0's 8 loads.
  STAGE_A_HALF(0, 0, 0);
  STAGE_A_HALF(0, 0, 1);
  STAGE_B_HALF(0, 0, 0);
  STAGE_B_HALF(0, 0, 1);
  STAGE_A_HALF(BK, 1, 0);
  __builtin_amdgcn_sched_barrier(0);
  asm volatile("s_waitcnt vmcnt(2)" ::: "memory");
  __builtin_amdgcn_s_barrier();
  __builtin_amdgcn_sched_barrier(0);

  for (int kt = 0; kt < NT; ++kt) {
    const int p = kt & 1;
    const unsigned short* Ab = &As[p * (BM * BK)];
    const unsigned short* Bb = &Bs[p * (BN * BK)];
    const int k1 = (kt + 1) * BK;
    const int k2 = (kt + 2) * BK;
    const bool pf1 = (kt + 1) < NT;
    const bool pf2 = (kt + 2) < NT;

    s16x8 af[4][2];        // current M-half A fragments
    s16x8 bf[2][2][2];     // both N-half B fragment sets (held across phases)

    // ---- phase 0: read af(m0)+bf(n0) [12 ds_read];
    //      stage A-h1(kt+1)+B-h0(kt+1) -> buf p^1 (dead tile kt-1)
    READ_AF(0);
    READ_BF(0);
    if (pf1) {
      STAGE_A_HALF(k1, p ^ 1, 1);
      STAGE_B_HALF(k1, p ^ 1, 0);
    }
    PHASE_BAR();
    MFMA_QUAD(0, 0);
    PHASE_BAR();

    // ---- phase 1: read bf(n1) [4 ds_read]; stage B-h1(kt+1) -> buf p^1
    READ_BF(1);
    if (pf1) STAGE_B_HALF(k1, p ^ 1, 1);
    PHASE_BAR();
    MFMA_QUAD(0, 1);
    PHASE_BAR();

    // ---- phase 2: read af(m1) [8 ds_read]; no stage (buf p still live)
    READ_AF(1);
    PHASE_BAR();
    MFMA_QUAD(1, 1);
    PHASE_BAR();

    // ---- phase 3: buf p now fully dead (all its reads lgkm-completed
    // before MFMA(1,1), then barrier) -> stage A-h0(kt+2) into it.
    // No barrier needed before MFMA(1,0) (no LDS reads this phase).
    if (pf2) STAGE_A_HALF(k2, p, 0);
    MFMA_QUAD(1, 0);
    __builtin_amdgcn_sched_barrier(0);
    if (kt < NT - 2) {
      asm volatile("s_waitcnt vmcnt(2)" ::: "memory");  // confirm tile kt+1
    } else {
      asm volatile("s_waitcnt vmcnt(0)" ::: "memory");  // tail: full confirm
    }
    PHASE_BAR();
  }

  // --- epilogue: C/D layout col=lane&15, row=quad*4+reg (unchanged order)
#pragma unroll
  for (int mi = 0; mi < 8; ++mi) {
#pragma unroll
    for (int ni = 0; ni < 4; ++ni) {
      const int o = bn + waveN + ni * 16 + l16;
#pragma unroll
      for (int r = 0; r < 4; ++r) {
        const int row = bm + waveM + mi * 16 + quad * 4 + r;
        C[(size_t)row * N_DIM + o] = acc[mi][ni][r];
      }
    }
  }
}

// ---------------------------------------------------------------------------
extern "C" void kernel_launch(void* const* d_in, const int* in_sizes, int n_in,
                              void* d_out, int out_size, void* d_ws, size_t ws_size,
                              hipStream_t stream) {
  const float* x        = (const float*)d_in[0];
  const int*   w_int    = (const int*)d_in[1];
  const float* w_scales = (const float*)d_in[2];
  const float* w_zeros  = (const float*)d_in[3];
  float* out = (float*)d_out;

  unsigned short* Aq = (unsigned short*)d_ws;                 // 8192*2048 bf16
  unsigned short* Wq = Aq + (size_t)M_DIM * K_DIM;            // 2048*2048 bf16

  const int prep_blocks = M_DIM + (N_DIM * (K_DIM / 8)) / 256;  // 8192 + 2048
  prep_kernel<<<prep_blocks, 256, 0, stream>>>(x, w_int, w_scales, w_zeros, Aq, Wq);
  dim3 grid(N_DIM / BN, M_DIM / BM);   // (8, 32) = 256 blocks = 1/CU
  gemm_kernel<<<grid, 512, 0, stream>>>(Aq, Wq, out);
}